// Round 6
// baseline (467.897 us; speedup 1.0000x reference)
//
#include <hip/hip_runtime.h>
#include <math.h>

// TemporalEncoder: out[t, b, d] = (t == floor(sigmoid(x[b,d]) * (T-1))) ? 1 : 0
// B=256, D=4096, T=100. Output 419 MB fp32, but only n=1M cells are 1.0f
// (one spike per (b,d)) -> 99% of the output is zeros.
//
// R7 algorithm change (after R0-R6 exhausted writer schedules):
//   Six structurally different "write every element" kernels (short blocks,
//   strided, 4-chunk ILP, persistent, persistent+nt, full-line nt) ALL
//   plateaued at ~3 TB/s effective, while __amd_rocclr_fillBufferAligned
//   sustains 6.25 TB/s on this same buffer every iteration. Rather than
//   beat the fill kernel, USE it:
//     1. hipMemsetAsync(out, 0)  -> dispatches fillBufferAligned, ~67 us
//        for 419 MB at fill-class BW. (Capture-legal: the harness's own
//        reset() enqueues hipMemsetAsync under graph capture.)
//     2. scatter_ones: read x (4 MB coalesced), compute spike time,
//        scatter 1M single-dword 1.0f stores (~64 MB dirty lines + ~64 MB
//        RFO fetch ~= 20 us). No st table, no pass-1.
//
// Counter-verified lessons kept for posterity:
//   R2: nt + lane-stride-64B stores -> 2.2x WRITE_SIZE (partial lines).
//   R3: 16 consecutive elems/thread breaks per-instruction coalescing.
//   R6: full-line nt == writeback (~3 TB/s) -> the ~3 TB/s wall was not an
//       L2 allocate/evict artifact; dense compute-stores just don't reach
//       the fill path's rate. Sparse scatter + memset sidesteps it.

typedef __attribute__((ext_vector_type(4))) float f32x4;

__device__ __forceinline__ float sigmoidf_(float x) {
    return 1.0f / (1.0f + expf(-x));  // matches f32 expit to 0 ulp vs np ref (R1)
}

__global__ __launch_bounds__(256) void scatter_ones_kernel(
    const float* __restrict__ x, float* __restrict__ out, int n, float tm1) {
    const int e = (blockIdx.x * 256 + threadIdx.x) * 4;
    if (e + 3 < n) {
        const f32x4 v = *reinterpret_cast<const f32x4*>(x + e);
        const int t0 = (int)(sigmoidf_(v.x) * tm1);
        const int t1 = (int)(sigmoidf_(v.y) * tm1);
        const int t2 = (int)(sigmoidf_(v.z) * tm1);
        const int t3 = (int)(sigmoidf_(v.w) * tm1);
        // 4 independent scattered dword stores (different t-planes).
        out[(size_t)t0 * n + (size_t)(e    )] = 1.0f;
        out[(size_t)t1 * n + (size_t)(e + 1)] = 1.0f;
        out[(size_t)t2 * n + (size_t)(e + 2)] = 1.0f;
        out[(size_t)t3 * n + (size_t)(e + 3)] = 1.0f;
    } else {
        for (int i = e; i < n; ++i) {
            const int t = (int)(sigmoidf_(x[i]) * tm1);
            out[(size_t)t * n + (size_t)i] = 1.0f;
        }
    }
}

extern "C" void kernel_launch(void* const* d_in, const int* in_sizes, int n_in,
                              void* d_out, int out_size, void* d_ws, size_t ws_size,
                              hipStream_t stream) {
    const float* x = (const float*)d_in[0];
    float* out = (float*)d_out;
    const int n = in_sizes[0];        // B*D = 1048576
    const float tm1 = (float)(out_size / n - 1);   // T-1 = 99

    // Zero the whole output via the rocclr fill path (6.2 TB/s measured on
    // this buffer every iteration), then scatter the 1M ones.
    hipMemsetAsync(d_out, 0, (size_t)out_size * sizeof(float), stream);

    const int n4 = (n + 3) / 4;
    const int blocks = (n4 + 255) / 256;   // 1024 for n = 2^20
    scatter_ones_kernel<<<blocks, 256, 0, stream>>>(x, out, n, tm1);
}